// Round 1
// baseline (1546.347 us; speedup 1.0000x reference)
//
#include <hip/hip_runtime.h>
#include <hip/hip_bf16.h>

// Problem constants (match reference)
#define NN 8192
#define KK 64
#define CARD 64
// ws layout (float offsets)
#define AST_OFF   0          // [64][8192] AS^T, 524288 floats
#define CRAW_OFF  524288     // [64][64]  CRAW[j*64+l] = C_ref[l][j]
#define DGM0_OFF  528384     // [64][2]
#define DGM1_OFF  528512     // [64][2]

#define L2E 1.4426950408889634f
#define LN2 0.6931471805599453f
#define LOG64 4.1588830833596715f

__device__ __forceinline__ float rlane(float v, int l) {
  return __int_as_float(__builtin_amdgcn_readlane(__float_as_int(v), l));
}

// ---------------------------------------------------------------------------
// K1: AS^T[j][row] += sum_k A[row][k] * S[k][j] over a 256-wide k chunk.
// lane = row; S row values are wave-uniform (scalar-promotable loads).
// grid = 128 row-groups * 32 k-chunks, block = 1 wave.
// ---------------------------------------------------------------------------
__global__ __launch_bounds__(64, 2) void k_gemm_as(
    const float* __restrict__ A, const float* __restrict__ S,
    float* __restrict__ AST) {
  const int rowblk = blockIdx.x & 127;
  const int kc = blockIdx.x >> 7;
  const int lane = threadIdx.x;
  const int row = rowblk * 64 + lane;
  const float* Arow = A + (size_t)row * NN + kc * 256;
  const float* Sb = S + (size_t)(kc * 256) * KK;

  float acc[64];
#pragma unroll
  for (int j = 0; j < 64; ++j) acc[j] = 0.0f;

  for (int kk = 0; kk < 256; kk += 4) {
    float4 a = *reinterpret_cast<const float4*>(Arow + kk);
    const float* Sr = Sb + kk * KK;
#pragma unroll
    for (int m = 0; m < 4; ++m) {
      const float am = (m == 0) ? a.x : (m == 1) ? a.y : (m == 2) ? a.z : a.w;
      const float4* Sv = reinterpret_cast<const float4*>(Sr + m * KK);
#pragma unroll
      for (int q = 0; q < 16; ++q) {
        float4 s4 = Sv[q];
        acc[4 * q + 0] = fmaf(am, s4.x, acc[4 * q + 0]);
        acc[4 * q + 1] = fmaf(am, s4.y, acc[4 * q + 1]);
        acc[4 * q + 2] = fmaf(am, s4.z, acc[4 * q + 2]);
        acc[4 * q + 3] = fmaf(am, s4.w, acc[4 * q + 3]);
      }
    }
  }
#pragma unroll
  for (int j = 0; j < 64; ++j)
    unsafeAtomicAdd(&AST[(size_t)j * NN + row], acc[j]);
}

// ---------------------------------------------------------------------------
// K2: CRAW[j*64+l] = C_ref[l][j] = sum_i S[i][l] * AS[i][j]
// block = column j of AS (64 blocks), 256 threads (lane=l, 4 i-segments).
// ---------------------------------------------------------------------------
__global__ __launch_bounds__(256) void k_gemm_c(
    const float* __restrict__ S, const float* __restrict__ AST,
    float* __restrict__ CRAW) {
  const int j = blockIdx.x;
  const int lane = threadIdx.x & 63;
  const int seg = threadIdx.x >> 6;
  const float* astj = AST + (size_t)j * NN + seg * 2048;
  float acc = 0.0f;
  for (int i = 0; i < 2048; i += 4) {
    float4 a4 = *reinterpret_cast<const float4*>(astj + i);
    const int ib = seg * 2048 + i;
    acc = fmaf(a4.x, S[(ib + 0) * KK + lane], acc);
    acc = fmaf(a4.y, S[(ib + 1) * KK + lane], acc);
    acc = fmaf(a4.z, S[(ib + 2) * KK + lane], acc);
    acc = fmaf(a4.w, S[(ib + 3) * KK + lane], acc);
  }
  __shared__ float red[4][64];
  red[seg][lane] = acc;
  __syncthreads();
  if (threadIdx.x < 64) {
    CRAW[j * 64 + lane] =
        red[0][lane] + red[1][lane] + red[2][lane] + red[3][lane];
  }
}

// ---------------------------------------------------------------------------
// K3: D build + Prim MST + dgm0 + dgm1 (one block, LDS-resident).
// Also zeroes d_out for K4's atomic adds.
// ---------------------------------------------------------------------------
__global__ __launch_bounds__(256) void k_topo(
    const float* __restrict__ CRAW, float* __restrict__ DGM0,
    float* __restrict__ DGM1, float* __restrict__ out) {
  __shared__ float Dl[64 * 66];
  __shared__ float red[4];
  __shared__ float wsE[64];
  __shared__ int usE[64], vsE[64];
  __shared__ unsigned char msk[4096];
  __shared__ float death[4096];
  __shared__ float pers[4096];
  __shared__ float rv[4];
  __shared__ int ri[4];
  const int t = threadIdx.x;

  if (t == 0) out[0] = 0.0f;

  // 1) symmetrize + global max
  float lmax = -1e30f;
#pragma unroll
  for (int m = 0; m < 16; ++m) {
    int idx = t + 256 * m;
    int a = idx >> 6, b = idx & 63;
    float v = 0.5f * (CRAW[idx] + CRAW[b * 64 + a]);
    Dl[a * 66 + b] = v;
    lmax = fmaxf(lmax, v);
  }
  for (int o = 32; o > 0; o >>= 1) lmax = fmaxf(lmax, __shfl_xor(lmax, o));
  if ((t & 63) == 0) red[t >> 6] = lmax;
  __syncthreads();
  const float mx = fmaxf(fmaxf(red[0], red[1]), fmaxf(red[2], red[3]));
  const float inv = 1.0f / (mx + 1e-12f);
  __syncthreads();
#pragma unroll
  for (int m = 0; m < 16; ++m) {
    int idx = t + 256 * m;
    int a = idx >> 6, b = idx & 63;
    float v = 1.0f - Dl[a * 66 + b] * inv;
    Dl[a * 66 + b] = (a == b) ? 0.0f : v;
  }
  __syncthreads();

  // 2) Prim MST in wave 0 (lane = vertex v)
  if (t < 64) {
    const int lane = t;
    bool intree = (lane == 0);
    float key = Dl[0 * 66 + lane];
    int par = 0;
    for (int step = 0; step < 63; ++step) {
      float kv = intree ? 1e9f : key;
      int ki = lane;
      for (int o = 32; o > 0; o >>= 1) {
        float ov = __shfl_xor(kv, o);
        int oi = __shfl_xor(ki, o);
        if (ov < kv || (ov == kv && oi < ki)) { kv = ov; ki = oi; }
      }
      int pu = __shfl(par, ki);
      if (lane == 0) { wsE[step] = kv; usE[step] = pu; vsE[step] = ki; }
      if (lane == ki) intree = true;
      float dn = Dl[ki * 66 + lane];
      if (!intree && dn < key) { key = dn; par = ki; }
    }
  }
  __syncthreads();

  // 3) MST adjacency mask
  for (int idx = t; idx < 4096; idx += 256) msk[idx] = 0;
  __syncthreads();
  if (t < 63) {
    int u = usE[t], v = vsE[t];
    msk[u * 64 + v] = 1;
    msk[v * 64 + u] = 1;
  }
  __syncthreads();

  // 4) dgm0: rank-sort descending of [ws(63), 0]
  if (t < 64) {
    float wv = (t < 63) ? wsE[t] : 0.0f;
    int rank = 0;
    for (int o = 0; o < 64; ++o) {
      float wo = (o < 63) ? wsE[o] : 0.0f;
      rank += (wo > wv) || (wo == wv && o < t);
    }
    DGM0[rank * 2 + 0] = 0.0f;
    DGM0[rank * 2 + 1] = wv;
  }

  // 5) death & persistence for all pairs
  for (int p = t; p < 4096; p += 256) {
    int i = p >> 6, j = p & 63;
    float dij = Dl[i * 66 + j];
    float tmin = 1e9f;
#pragma unroll 8
    for (int k2 = 0; k2 < 64; ++k2) {
      float m2 = fmaxf(Dl[i * 66 + k2], Dl[j * 66 + k2]);
      tmin = fminf(tmin, (k2 == i || k2 == j) ? 1e9f : m2);
    }
    float de = fmaxf(dij, tmin);
    death[p] = de;
    bool valid = (j > i) && (!msk[p]);
    pers[p] = valid ? (de - dij) : -1.0f;
  }
  __syncthreads();

  // 6) top-64 of pers (lowest-index ties), write dgm1
  for (int r = 0; r < 64; ++r) {
    float bv = -1e30f;
    int bi = 0;
    for (int p = t; p < 4096; p += 256) {
      float v = pers[p];
      if (v > bv) { bv = v; bi = p; }
    }
    for (int o = 32; o > 0; o >>= 1) {
      float ov = __shfl_xor(bv, o);
      int oi = __shfl_xor(bi, o);
      if (ov > bv || (ov == bv && oi < bi)) { bv = ov; bi = oi; }
    }
    if ((t & 63) == 0) { rv[t >> 6] = bv; ri[t >> 6] = bi; }
    __syncthreads();
    if (t == 0) {
      for (int q = 1; q < 4; ++q)
        if (rv[q] > bv || (rv[q] == bv && ri[q] < bi)) { bv = rv[q]; bi = ri[q]; }
      bool keep = bv > 0.0f;
      int i = bi >> 6, j = bi & 63;
      DGM1[r * 2 + 0] = keep ? Dl[i * 66 + j] : 0.0f;
      DGM1[r * 2 + 1] = keep ? death[bi] : 0.0f;
      pers[bi] = -3.0f;
    }
    __syncthreads();
  }
}

// ---------------------------------------------------------------------------
// K4: entropic Sinkhorn W1 (65x65, 300 iters), 4 independent problems.
// lane = row (phase f) / col (phase g); cost chunk in registers;
// f/g broadcast via v_readlane (VALU pipe); 2 barriers / iteration.
// ---------------------------------------------------------------------------
__global__ __launch_bounds__(512) void k_sinkhorn(
    const float* __restrict__ DGM0, const float* __restrict__ DGM1,
    const float* __restrict__ G0, const float* __restrict__ G1,
    const float* __restrict__ G2, const float* __restrict__ G3,
    float* __restrict__ out) {
  const int b = blockIdx.x;
  const float* X = (b & 1) ? DGM1 : DGM0;
  const float* Y = (b == 0) ? G0 : (b == 1) ? G1 : (b == 2) ? G2 : G3;

  __shared__ float Ce[65 * 66];     // C / eps
  __shared__ float2 pmf[8][66];     // (max, sum) partials, phase f
  __shared__ float2 pmg[8][66];     // phase g
  __shared__ float fs64_s, gs64_s;
  __shared__ float wsum[8];

  const int t = threadIdx.x;
  const int lane = t & 63;
  const int w = t >> 6;
  const float INVE = 100.0f;  // 1/eps

  for (int idx = t; idx < 65 * 65; idx += 512) {
    int i = idx / 65, j = idx - i * 65;
    float v;
    if (i < 64) {
      float xb = X[i * 2], xd = X[i * 2 + 1];
      if (j < 64)
        v = fmaxf(fabsf(xb - Y[j * 2]), fabsf(xd - Y[j * 2 + 1]));
      else
        v = 0.5f * (xd - xb);
    } else {
      v = (j < 64) ? 0.5f * (Y[j * 2 + 1] - Y[j * 2]) : 0.0f;
    }
    Ce[i * 66 + j] = v * INVE;
  }
  if (t == 0) { fs64_s = 0.0f; gs64_s = 0.0f; }
  __syncthreads();

  // register-resident cost chunks (reused 300x)
  float CF[8], CG[8];
#pragma unroll
  for (int q = 0; q < 8; ++q) {
    CF[q] = Ce[lane * 66 + (8 * w + q)];  // my row, my j-chunk
    CG[q] = Ce[(8 * w + q) * 66 + lane];  // my col, my i-chunk
  }
  const float CF8 = Ce[lane * 66 + 64];  // Ce[row=lane][64]
  const float CG8 = Ce[64 * 66 + lane];  // Ce[64][col=lane]

  float fs_r = 0.0f, gs_r = 0.0f;  // scaled potentials, replicated per wave
  float fs64 = 0.0f, gs64 = 0.0f;

  for (int it = 0; it < 300; ++it) {
    // ---- phase f (lane = row i) ----
    {
      float vv[9];
      float m = -3.0e38f;
#pragma unroll
      for (int q = 0; q < 8; ++q) {
        float gq = rlane(gs_r, 8 * w + q);
        vv[q] = gq - CF[q];
        m = fmaxf(m, vv[q]);
      }
      if (w == 7) { vv[8] = gs64 - CF8; m = fmaxf(m, vv[8]); }
      float s = 0.0f;
#pragma unroll
      for (int q = 0; q < 8; ++q) s += exp2f((vv[q] - m) * L2E);
      if (w == 7) s += exp2f((vv[8] - m) * L2E);
      pmf[w][lane] = make_float2(m, s);
      if (w == 7) {  // row 64 LSE over all j
        float v = gs_r - CG8;
        float vx = (lane == 0) ? gs64 : -3.0e38f;  // j=64, Ce[64][64]=0
        float mm = fmaxf(v, vx);
        for (int o = 32; o > 0; o >>= 1) mm = fmaxf(mm, __shfl_xor(mm, o));
        float e = exp2f((v - mm) * L2E);
        if (lane == 0) e += exp2f((vx - mm) * L2E);
        for (int o = 32; o > 0; o >>= 1) e += __shfl_xor(e, o);
        if (lane == 0) fs64_s = LOG64 - (mm + LN2 * log2f(e));
      }
      __syncthreads();
      float mq[8], sq[8];
#pragma unroll
      for (int q2 = 0; q2 < 8; ++q2) {
        float2 p = pmf[q2][lane];
        mq[q2] = p.x; sq[q2] = p.y;
      }
      float M = mq[0];
#pragma unroll
      for (int q2 = 1; q2 < 8; ++q2) M = fmaxf(M, mq[q2]);
      float ss = 0.0f;
#pragma unroll
      for (int q2 = 0; q2 < 8; ++q2) ss += sq[q2] * exp2f((mq[q2] - M) * L2E);
      fs_r = 0.0f - (M + LN2 * log2f(ss));  // loga = 0 for rows 0..63
      fs64 = fs64_s;
    }
    // ---- phase g (lane = col j) ----
    {
      float vv[9];
      float m = -3.0e38f;
#pragma unroll
      for (int q = 0; q < 8; ++q) {
        float fq = rlane(fs_r, 8 * w + q);
        vv[q] = fq - CG[q];
        m = fmaxf(m, vv[q]);
      }
      if (w == 7) { vv[8] = fs64 - CG8; m = fmaxf(m, vv[8]); }
      float s = 0.0f;
#pragma unroll
      for (int q = 0; q < 8; ++q) s += exp2f((vv[q] - m) * L2E);
      if (w == 7) s += exp2f((vv[8] - m) * L2E);
      pmg[w][lane] = make_float2(m, s);
      if (w == 7) {  // col 64 LSE over all i
        float v = fs_r - CF8;
        float vx = (lane == 0) ? fs64 : -3.0e38f;  // i=64
        float mm = fmaxf(v, vx);
        for (int o = 32; o > 0; o >>= 1) mm = fmaxf(mm, __shfl_xor(mm, o));
        float e = exp2f((v - mm) * L2E);
        if (lane == 0) e += exp2f((vx - mm) * L2E);
        for (int o = 32; o > 0; o >>= 1) e += __shfl_xor(e, o);
        if (lane == 0) gs64_s = LOG64 - (mm + LN2 * log2f(e));
      }
      __syncthreads();
      float mq[8], sq[8];
#pragma unroll
      for (int q2 = 0; q2 < 8; ++q2) {
        float2 p = pmg[q2][lane];
        mq[q2] = p.x; sq[q2] = p.y;
      }
      float M = mq[0];
#pragma unroll
      for (int q2 = 1; q2 < 8; ++q2) M = fmaxf(M, mq[q2]);
      float ss = 0.0f;
#pragma unroll
      for (int q2 = 0; q2 < 8; ++q2) ss += sq[q2] * exp2f((mq[q2] - M) * L2E);
      gs_r = 0.0f - (M + LN2 * log2f(ss));  // logb = 0 for cols 0..63
      gs64 = gs64_s;
    }
  }

  // ---- final: sum P * C  (C = Ce * eps) ----
  float acc = 0.0f;
#pragma unroll
  for (int q = 0; q < 8; ++q) {
    float gq = rlane(gs_r, 8 * w + q);
    acc += exp2f((fs_r + gq - CF[q]) * L2E) * CF[q];
  }
  if (w == 7) {
    acc += exp2f((fs_r + gs64 - CF8) * L2E) * CF8;  // col 64, rows = lane
    acc += exp2f((fs64 + gs_r - CG8) * L2E) * CG8;  // row 64, cols = lane
    // (64,64): C = 0 contributes nothing
  }
  for (int o = 32; o > 0; o >>= 1) acc += __shfl_xor(acc, o);
  if (lane == 0) wsum[w] = acc;
  __syncthreads();
  if (t == 0) {
    float tot = 0.0f;
#pragma unroll
    for (int q = 0; q < 8; ++q) tot += wsum[q];
    atomicAdd(out, 0.1f * 0.01f * tot);  // LAMBDA * eps * sum(exp * Ce)
  }
}

// ---------------------------------------------------------------------------
extern "C" void kernel_launch(void* const* d_in, const int* in_sizes, int n_in,
                              void* d_out, int out_size, void* d_ws,
                              size_t ws_size, hipStream_t stream) {
  const float* A = (const float*)d_in[0];
  const float* S = (const float*)d_in[1];
  const float* G0 = (const float*)d_in[2];
  const float* G1 = (const float*)d_in[3];
  const float* G2 = (const float*)d_in[4];
  const float* G3 = (const float*)d_in[5];
  float* out = (float*)d_out;
  float* ws = (float*)d_ws;

  float* AST = ws + AST_OFF;
  float* CRAW = ws + CRAW_OFF;
  float* DGM0 = ws + DGM0_OFF;
  float* DGM1 = ws + DGM1_OFF;

  hipMemsetAsync(AST, 0, (size_t)64 * NN * sizeof(float), stream);

  k_gemm_as<<<dim3(4096), dim3(64), 0, stream>>>(A, S, AST);
  k_gemm_c<<<dim3(64), dim3(256), 0, stream>>>(S, AST, CRAW);
  k_topo<<<dim3(1), dim3(256), 0, stream>>>(CRAW, DGM0, DGM1, out);
  k_sinkhorn<<<dim3(4), dim3(512), 0, stream>>>(DGM0, DGM1, G0, G1, G2, G3,
                                                out);
}

// Round 3
// 1295.718 us; speedup vs baseline: 1.1934x; 1.1934x over previous
//
#include <hip/hip_runtime.h>
#include <hip/hip_bf16.h>

// Problem constants (match reference)
#define NN 8192
#define KK 64
#define CARD 64
// ws layout (float offsets)
#define AST_OFF   0          // [64][8192] AS^T, 524288 floats
#define CRAW_OFF  524288     // [64][64]  CRAW[j*64+l] = C_ref[l][j]
#define DGM0_OFF  528384     // [64][2]
#define DGM1_OFF  528512     // [64][2]

#define L2E 1.4426950408889634f
#define LN2 0.6931471805599453f
#define LOG64 4.1588830833596715f

__device__ __forceinline__ float rlane(float v, int l) {
  return __int_as_float(__builtin_amdgcn_readlane(__float_as_int(v), l));
}

// ---- DPP wave64 reductions (VALU pipe, no LDS) ------------------------------
// ctrl/rmask must be immediates -> template parameters.
// max: invalid/masked source lanes keep old value (identity for fmax)
template <int CTRL, int RMASK>
__device__ __forceinline__ float dpp_keep(float v) {
  return __int_as_float(__builtin_amdgcn_update_dpp(
      __float_as_int(v), __float_as_int(v), CTRL, RMASK, 0xf, false));
}
// sum: invalid/masked source lanes produce 0 (identity for add)
template <int CTRL, int RMASK>
__device__ __forceinline__ float dpp_zero(float v) {
  return __int_as_float(__builtin_amdgcn_update_dpp(
      0, __float_as_int(v), CTRL, RMASK, 0xf, true));
}
// result valid in lane 63
__device__ __forceinline__ float wave_max63(float v) {
  v = fmaxf(v, dpp_keep<0x111, 0xf>(v));  // row_shr:1
  v = fmaxf(v, dpp_keep<0x112, 0xf>(v));  // row_shr:2
  v = fmaxf(v, dpp_keep<0x114, 0xf>(v));  // row_shr:4
  v = fmaxf(v, dpp_keep<0x118, 0xf>(v));  // row_shr:8
  v = fmaxf(v, dpp_keep<0x142, 0xa>(v));  // row_bcast:15 -> rows 1,3
  v = fmaxf(v, dpp_keep<0x143, 0xc>(v));  // row_bcast:31 -> rows 2,3
  return v;
}
__device__ __forceinline__ float wave_sum63(float v) {
  v += dpp_zero<0x111, 0xf>(v);
  v += dpp_zero<0x112, 0xf>(v);
  v += dpp_zero<0x114, 0xf>(v);
  v += dpp_zero<0x118, 0xf>(v);
  v += dpp_zero<0x142, 0xa>(v);
  v += dpp_zero<0x143, 0xc>(v);
  return v;
}

// ---------------------------------------------------------------------------
// K1: AS^T[j][row] += A @ S over a k-split chunk.
// 256 thr = 64 rows x 4 colgroups (cg wave-uniform -> S via scalar loads).
// A tile staged in LDS (stride 129: 2-way bank alias = free).
// grid = 128 rowblocks * 8 ksplit.
// ---------------------------------------------------------------------------
#define KSPLIT 8
#define KT 128
__global__ __launch_bounds__(256) void k_gemm_as(
    const float* __restrict__ A, const float* __restrict__ S,
    float* __restrict__ AST) {
  __shared__ float At[64][129];
  const int rb = blockIdx.x >> 3;
  const int ks = blockIdx.x & 7;
  const int row = threadIdx.x & 63;
  const int cg = __builtin_amdgcn_readfirstlane(threadIdx.x >> 6);
  const int r0 = rb * 64;

  float acc[16];
#pragma unroll
  for (int q = 0; q < 16; ++q) acc[q] = 0.0f;

  const int kbeg = ks * (NN / KSPLIT);
  for (int kt = kbeg; kt < kbeg + NN / KSPLIT; kt += KT) {
    // stage A[r0..r0+63][kt..kt+KT) -- fully coalesced (2 rows per wave-load)
#pragma unroll
    for (int q = 0; q < 8; ++q) {
      int fi = q * 256 + threadIdx.x;      // float4 index in 64x128 tile
      int rr = fi >> 5, cc = (fi & 31) * 4;
      float4 v = *reinterpret_cast<const float4*>(
          A + (size_t)(r0 + rr) * NN + kt + cc);
      At[rr][cc + 0] = v.x; At[rr][cc + 1] = v.y;
      At[rr][cc + 2] = v.z; At[rr][cc + 3] = v.w;
    }
    __syncthreads();
    const float* Sb = S + (size_t)kt * KK + cg * 16;
#pragma unroll 4
    for (int k = 0; k < KT; ++k) {
      float a = At[row][k];
      const float4* Sv = reinterpret_cast<const float4*>(Sb + (size_t)k * KK);
      float4 s0 = Sv[0], s1 = Sv[1], s2 = Sv[2], s3 = Sv[3];
      acc[0]  = fmaf(a, s0.x, acc[0]);  acc[1]  = fmaf(a, s0.y, acc[1]);
      acc[2]  = fmaf(a, s0.z, acc[2]);  acc[3]  = fmaf(a, s0.w, acc[3]);
      acc[4]  = fmaf(a, s1.x, acc[4]);  acc[5]  = fmaf(a, s1.y, acc[5]);
      acc[6]  = fmaf(a, s1.z, acc[6]);  acc[7]  = fmaf(a, s1.w, acc[7]);
      acc[8]  = fmaf(a, s2.x, acc[8]);  acc[9]  = fmaf(a, s2.y, acc[9]);
      acc[10] = fmaf(a, s2.z, acc[10]); acc[11] = fmaf(a, s2.w, acc[11]);
      acc[12] = fmaf(a, s3.x, acc[12]); acc[13] = fmaf(a, s3.y, acc[13]);
      acc[14] = fmaf(a, s3.z, acc[14]); acc[15] = fmaf(a, s3.w, acc[15]);
    }
    __syncthreads();
  }
#pragma unroll
  for (int q = 0; q < 16; ++q)
    unsafeAtomicAdd(&AST[(size_t)(cg * 16 + q) * NN + r0 + row], acc[q]);
}

// ---------------------------------------------------------------------------
// K2: CRAW[j*64+l] += sum_i S[i][l] * AST[j][i]  over an i-segment.
// grid = 64 j * 8 iseg; AST side via scalar loads (uniform address).
// ---------------------------------------------------------------------------
__global__ __launch_bounds__(256) void k_gemm_c(
    const float* __restrict__ S, const float* __restrict__ AST,
    float* __restrict__ CRAW) {
  const int j = blockIdx.x & 63;
  const int iseg = blockIdx.x >> 6;
  const int lane = threadIdx.x & 63;
  const int s4 = __builtin_amdgcn_readfirstlane(threadIdx.x >> 6);
  const int i0 = iseg * 1024 + s4 * 256;
  const float* astj = AST + (size_t)j * NN + i0;
  float acc = 0.0f;
  for (int i = 0; i < 256; i += 4) {
    float4 a4 = *reinterpret_cast<const float4*>(astj + i);
    const float* Srow = S + (size_t)(i0 + i) * KK + lane;
    acc = fmaf(a4.x, Srow[0 * KK], acc);
    acc = fmaf(a4.y, Srow[1 * KK], acc);
    acc = fmaf(a4.z, Srow[2 * KK], acc);
    acc = fmaf(a4.w, Srow[3 * KK], acc);
  }
  __shared__ float red[4][64];
  red[s4][lane] = acc;
  __syncthreads();
  if (threadIdx.x < 64) {
    unsafeAtomicAdd(&CRAW[j * 64 + lane],
                    red[0][lane] + red[1][lane] + red[2][lane] + red[3][lane]);
  }
}

// ---------------------------------------------------------------------------
// K3: D build + Prim MST + dgm0 + dgm1 (one block, LDS-resident).
// Also zeroes d_out for K4's atomic adds.
// ---------------------------------------------------------------------------
__global__ __launch_bounds__(256) void k_topo(
    const float* __restrict__ CRAW, float* __restrict__ DGM0,
    float* __restrict__ DGM1, float* __restrict__ out) {
  __shared__ float Dl[64 * 66];
  __shared__ float red[4];
  __shared__ float wsE[64];
  __shared__ int usE[64], vsE[64];
  __shared__ unsigned char msk[4096];
  __shared__ float death[4096];
  __shared__ float pers[4096];
  __shared__ float rv[4];
  __shared__ int ri[4];
  const int t = threadIdx.x;

  if (t == 0) out[0] = 0.0f;

  // 1) symmetrize + global max
  float lmax = -1e30f;
#pragma unroll
  for (int m = 0; m < 16; ++m) {
    int idx = t + 256 * m;
    int a = idx >> 6, b = idx & 63;
    float v = 0.5f * (CRAW[idx] + CRAW[b * 64 + a]);
    Dl[a * 66 + b] = v;
    lmax = fmaxf(lmax, v);
  }
  for (int o = 32; o > 0; o >>= 1) lmax = fmaxf(lmax, __shfl_xor(lmax, o));
  if ((t & 63) == 0) red[t >> 6] = lmax;
  __syncthreads();
  const float mx = fmaxf(fmaxf(red[0], red[1]), fmaxf(red[2], red[3]));
  const float inv = 1.0f / (mx + 1e-12f);
  __syncthreads();
#pragma unroll
  for (int m = 0; m < 16; ++m) {
    int idx = t + 256 * m;
    int a = idx >> 6, b = idx & 63;
    float v = 1.0f - Dl[a * 66 + b] * inv;
    Dl[a * 66 + b] = (a == b) ? 0.0f : v;
  }
  __syncthreads();

  // 2) Prim MST in wave 0 (lane = vertex v)
  if (t < 64) {
    const int lane = t;
    bool intree = (lane == 0);
    float key = Dl[0 * 66 + lane];
    int par = 0;
    for (int step = 0; step < 63; ++step) {
      float kv = intree ? 1e9f : key;
      int ki = lane;
      for (int o = 32; o > 0; o >>= 1) {
        float ov = __shfl_xor(kv, o);
        int oi = __shfl_xor(ki, o);
        if (ov < kv || (ov == kv && oi < ki)) { kv = ov; ki = oi; }
      }
      int pu = __shfl(par, ki);
      if (lane == 0) { wsE[step] = kv; usE[step] = pu; vsE[step] = ki; }
      if (lane == ki) intree = true;
      float dn = Dl[ki * 66 + lane];
      if (!intree && dn < key) { key = dn; par = ki; }
    }
  }
  __syncthreads();

  // 3) MST adjacency mask
  for (int idx = t; idx < 4096; idx += 256) msk[idx] = 0;
  __syncthreads();
  if (t < 63) {
    int u = usE[t], v = vsE[t];
    msk[u * 64 + v] = 1;
    msk[v * 64 + u] = 1;
  }
  __syncthreads();

  // 4) dgm0: rank-sort descending of [ws(63), 0]
  if (t < 64) {
    float wv = (t < 63) ? wsE[t] : 0.0f;
    int rank = 0;
    for (int o = 0; o < 64; ++o) {
      float wo = (o < 63) ? wsE[o] : 0.0f;
      rank += (wo > wv) || (wo == wv && o < t);
    }
    DGM0[rank * 2 + 0] = 0.0f;
    DGM0[rank * 2 + 1] = wv;
  }

  // 5) death & persistence for all pairs
  for (int p = t; p < 4096; p += 256) {
    int i = p >> 6, j = p & 63;
    float dij = Dl[i * 66 + j];
    float tmin = 1e9f;
#pragma unroll 8
    for (int k2 = 0; k2 < 64; ++k2) {
      float m2 = fmaxf(Dl[i * 66 + k2], Dl[j * 66 + k2]);
      tmin = fminf(tmin, (k2 == i || k2 == j) ? 1e9f : m2);
    }
    float de = fmaxf(dij, tmin);
    death[p] = de;
    bool valid = (j > i) && (!msk[p]);
    pers[p] = valid ? (de - dij) : -1.0f;
  }
  __syncthreads();

  // 6) top-64 of pers (lowest-index ties), write dgm1
  for (int r = 0; r < 64; ++r) {
    float bv = -1e30f;
    int bi = 0;
    for (int p = t; p < 4096; p += 256) {
      float v = pers[p];
      if (v > bv) { bv = v; bi = p; }
    }
    for (int o = 32; o > 0; o >>= 1) {
      float ov = __shfl_xor(bv, o);
      int oi = __shfl_xor(bi, o);
      if (ov > bv || (ov == bv && oi < bi)) { bv = ov; bi = oi; }
    }
    if ((t & 63) == 0) { rv[t >> 6] = bv; ri[t >> 6] = bi; }
    __syncthreads();
    if (t == 0) {
      for (int q = 1; q < 4; ++q)
        if (rv[q] > bv || (rv[q] == bv && ri[q] < bi)) { bv = rv[q]; bi = ri[q]; }
      bool keep = bv > 0.0f;
      int i = bi >> 6, j = bi & 63;
      DGM1[r * 2 + 0] = keep ? Dl[i * 66 + j] : 0.0f;
      DGM1[r * 2 + 1] = keep ? death[bi] : 0.0f;
      pers[bi] = -3.0f;
    }
    __syncthreads();
  }
}

// ---------------------------------------------------------------------------
// K4: entropic Sinkhorn W1 (65x65, 300 iters), 4 independent problems.
// All cross-lane reductions on the VALU pipe (DPP); row/col-64 LSE computed
// redundantly per wave (no LDS round-trip, no barrier coupling).
// Per phase: 1 ds_write_b64 + 1 barrier + 8 ds_read_b64.
// ---------------------------------------------------------------------------
__global__ __launch_bounds__(512) void k_sinkhorn(
    const float* __restrict__ DGM0, const float* __restrict__ DGM1,
    const float* __restrict__ G0, const float* __restrict__ G1,
    const float* __restrict__ G2, const float* __restrict__ G3,
    float* __restrict__ out) {
  const int b = blockIdx.x;
  const float* X = (b & 1) ? DGM1 : DGM0;
  const float* Y = (b == 0) ? G0 : (b == 1) ? G1 : (b == 2) ? G2 : G3;

  __shared__ float Ce[65 * 66];   // C / eps
  __shared__ float2 pmf[8][66];   // (max, sum) partials, phase f
  __shared__ float2 pmg[8][66];   // phase g
  __shared__ float wsum[8];

  const int t = threadIdx.x;
  const int lane = t & 63;
  const int w = __builtin_amdgcn_readfirstlane(t >> 6);
  const float INVE = 100.0f;  // 1/eps

  for (int idx = t; idx < 65 * 65; idx += 512) {
    int i = idx / 65, j = idx - i * 65;
    float v;
    if (i < 64) {
      float xb = X[i * 2], xd = X[i * 2 + 1];
      if (j < 64)
        v = fmaxf(fabsf(xb - Y[j * 2]), fabsf(xd - Y[j * 2 + 1]));
      else
        v = 0.5f * (xd - xb);
    } else {
      v = (j < 64) ? 0.5f * (Y[j * 2 + 1] - Y[j * 2]) : 0.0f;
    }
    Ce[i * 66 + j] = v * INVE;
  }
  __syncthreads();

  // register-resident cost chunks (reused 300x)
  float CF[8], CG[8];
#pragma unroll
  for (int q = 0; q < 8; ++q) {
    CF[q] = Ce[lane * 66 + (8 * w + q)];  // row=lane, col=8w+q  (f phase)
    CG[q] = Ce[(8 * w + q) * 66 + lane];  // row=8w+q, col=lane  (g phase)
  }
  const float CF8 = Ce[lane * 66 + 64];  // Ce[i=lane][64]
  const float C64 = Ce[64 * 66 + lane];  // Ce[64][j=lane]

  float fs = 0.0f, gs = 0.0f;     // potentials / eps, replicated per wave
  float fs64 = 0.0f, gs64 = 0.0f;

  for (int it = 0; it < 300; ++it) {
    // ================= phase f (rows) =================
    // row-64 LSE over j=0..64 (redundant per wave, DPP on VALU pipe)
    float f64n;
    {
      float wv = gs - C64;                       // j = lane
      float mR = rlane(wave_max63(wv), 63);
      mR = fmaxf(mR, gs64);                      // j = 64 term (Ce[64][64]=0)
      float e = exp2f((wv - mR) * L2E);
      float sR = rlane(wave_sum63(e), 63) + exp2f((gs64 - mR) * L2E);
      f64n = LOG64 - (mR + LN2 * log2f(sR));
    }
    // main: rows 0..63, this wave's 8-col chunk
    {
      float vq[8];
      float m = -3.0e38f;
#pragma unroll
      for (int q = 0; q < 8; ++q) {
        vq[q] = rlane(gs, 8 * w + q) - CF[q];
        m = fmaxf(m, vq[q]);
      }
      float v8 = 0.0f;
      if (w == 7) { v8 = gs64 - CF8; m = fmaxf(m, v8); }
      float s = 0.0f;
#pragma unroll
      for (int q = 0; q < 8; ++q) s += exp2f((vq[q] - m) * L2E);
      if (w == 7) s += exp2f((v8 - m) * L2E);
      pmf[w][lane] = make_float2(m, s);
    }
    __syncthreads();
    {
      float mq[8], sq[8];
#pragma unroll
      for (int q2 = 0; q2 < 8; ++q2) {
        float2 p = pmf[q2][lane];
        mq[q2] = p.x; sq[q2] = p.y;
      }
      float M = mq[0];
#pragma unroll
      for (int q2 = 1; q2 < 8; ++q2) M = fmaxf(M, mq[q2]);
      float ss = 0.0f;
#pragma unroll
      for (int q2 = 0; q2 < 8; ++q2) ss += sq[q2] * exp2f((mq[q2] - M) * L2E);
      fs = 0.0f - (M + LN2 * log2f(ss));  // loga = 0 for rows 0..63
    }
    fs64 = f64n;

    // ================= phase g (cols) =================
    // col-64 LSE over i=0..64 (redundant per wave)
    float g64n;
    {
      float wv = fs - CF8;                       // i = lane
      float mC = rlane(wave_max63(wv), 63);
      mC = fmaxf(mC, fs64);                      // i = 64 term
      float e = exp2f((wv - mC) * L2E);
      float sC = rlane(wave_sum63(e), 63) + exp2f((fs64 - mC) * L2E);
      g64n = LOG64 - (mC + LN2 * log2f(sC));
    }
    // main: cols 0..63, this wave's 8-row chunk
    {
      float vq[8];
      float m = -3.0e38f;
#pragma unroll
      for (int q = 0; q < 8; ++q) {
        vq[q] = rlane(fs, 8 * w + q) - CG[q];
        m = fmaxf(m, vq[q]);
      }
      float v8 = 0.0f;
      if (w == 7) { v8 = fs64 - C64; m = fmaxf(m, v8); }
      float s = 0.0f;
#pragma unroll
      for (int q = 0; q < 8; ++q) s += exp2f((vq[q] - m) * L2E);
      if (w == 7) s += exp2f((v8 - m) * L2E);
      pmg[w][lane] = make_float2(m, s);
    }
    __syncthreads();
    {
      float mq[8], sq[8];
#pragma unroll
      for (int q2 = 0; q2 < 8; ++q2) {
        float2 p = pmg[q2][lane];
        mq[q2] = p.x; sq[q2] = p.y;
      }
      float M = mq[0];
#pragma unroll
      for (int q2 = 1; q2 < 8; ++q2) M = fmaxf(M, mq[q2]);
      float ss = 0.0f;
#pragma unroll
      for (int q2 = 0; q2 < 8; ++q2) ss += sq[q2] * exp2f((mq[q2] - M) * L2E);
      gs = 0.0f - (M + LN2 * log2f(ss));  // logb = 0 for cols 0..63
    }
    gs64 = g64n;
  }

  // ---- final: sum P * C  (C = Ce * eps) ----
  float acc = 0.0f;
#pragma unroll
  for (int q = 0; q < 8; ++q) {
    float gq = rlane(gs, 8 * w + q);
    acc += exp2f((fs + gq - CF[q]) * L2E) * CF[q];
  }
  if (w == 7) {
    acc += exp2f((fs + gs64 - CF8) * L2E) * CF8;  // col 64, rows = lane
    acc += exp2f((fs64 + gs - C64) * L2E) * C64;  // row 64, cols = lane
    // (64,64): C = 0 contributes nothing
  }
  acc = rlane(wave_sum63(acc), 63);
  if (lane == 0) wsum[w] = acc;
  __syncthreads();
  if (t == 0) {
    float tot = 0.0f;
#pragma unroll
    for (int q = 0; q < 8; ++q) tot += wsum[q];
    atomicAdd(out, 0.1f * 0.01f * tot);  // LAMBDA * eps * sum(P * Ce)
  }
}

// ---------------------------------------------------------------------------
extern "C" void kernel_launch(void* const* d_in, const int* in_sizes, int n_in,
                              void* d_out, int out_size, void* d_ws,
                              size_t ws_size, hipStream_t stream) {
  const float* A = (const float*)d_in[0];
  const float* S = (const float*)d_in[1];
  const float* G0 = (const float*)d_in[2];
  const float* G1 = (const float*)d_in[3];
  const float* G2 = (const float*)d_in[4];
  const float* G3 = (const float*)d_in[5];
  float* out = (float*)d_out;
  float* ws = (float*)d_ws;

  float* AST = ws + AST_OFF;
  float* CRAW = ws + CRAW_OFF;
  float* DGM0 = ws + DGM0_OFF;
  float* DGM1 = ws + DGM1_OFF;

  // zero AST (2 MB) + CRAW (16 KB) for atomic accumulation
  (void)hipMemsetAsync(AST, 0, (size_t)(64 * NN + 64 * 64) * sizeof(float),
                       stream);

  k_gemm_as<<<dim3(128 * KSPLIT), dim3(256), 0, stream>>>(A, S, AST);
  k_gemm_c<<<dim3(64 * 8), dim3(256), 0, stream>>>(S, AST, CRAW);
  k_topo<<<dim3(1), dim3(256), 0, stream>>>(CRAW, DGM0, DGM1, out);
  k_sinkhorn<<<dim3(4), dim3(512), 0, stream>>>(DGM0, DGM1, G0, G1, G2, G3,
                                                out);
}

// Round 4
// 896.645 us; speedup vs baseline: 1.7246x; 1.4451x over previous
//
#include <hip/hip_runtime.h>
#include <hip/hip_bf16.h>

// Problem constants (match reference)
#define NN 8192
#define KK 64
#define CARD 64
// ws layout (float offsets)
#define AST_OFF   0          // [64][8192] AS^T, 524288 floats
#define CRAW_OFF  524288     // [64][64]  CRAW[j*64+l] = C_ref[l][j]
#define DGM0_OFF  528384     // [64][2]
#define DGM1_OFF  528512     // [64][2]

__device__ __forceinline__ float rlane(float v, int l) {
  return __int_as_float(__builtin_amdgcn_readlane(__float_as_int(v), l));
}
__device__ __forceinline__ double rdlane(double x, int l) {
  int lo = __builtin_amdgcn_readlane(__double2loint(x), l);
  int hi = __builtin_amdgcn_readlane(__double2hiint(x), l);
  return __hiloint2double(hi, lo);
}

// ---------------------------------------------------------------------------
// K1: AS^T[j][row] += A @ S over a k-split chunk.
// 256 thr = 4 waves; wave = 16-col group (cg); lane = base row; 4 rows/lane
// (rows lane, lane+64, lane+128, lane+192) -> 64 fma per 8 LDS reads.
// A tile k-major in LDS (conflict-free b32); S tile in LDS, wave-uniform
// b128 broadcast reads. grid = 32 rowblocks * 16 ksplit = 512 (2 blocks/CU).
// ---------------------------------------------------------------------------
#define KSPLIT 16
#define KT 32
#define RB 256
__global__ __launch_bounds__(256, 2) void k_gemm_as(
    const float* __restrict__ A, const float* __restrict__ S,
    float* __restrict__ AST) {
  __shared__ float At[KT][RB + 1];   // k-major: At[k][row], 32.9 KB
  __shared__ float Sl[KT][64];       // 8 KB
  const int tid = threadIdx.x;
  const int rb = blockIdx.x >> 4;
  const int ks = blockIdx.x & 15;
  const int r0 = rb * RB;
  const int lane = tid & 63;
  const int cg = __builtin_amdgcn_readfirstlane(tid >> 6);
  const int c0 = cg * 16;

  float acc[4][16];
#pragma unroll
  for (int r = 0; r < 4; ++r)
#pragma unroll
    for (int q = 0; q < 16; ++q) acc[r][q] = 0.0f;

  const int kbeg = ks * (NN / KSPLIT);  // 512 k per block
  for (int kt = kbeg; kt < kbeg + NN / KSPLIT; kt += KT) {
    // stage A: 256 rows x 32 k = 2048 float4, 8 per thread
#pragma unroll
    for (int p = 0; p < 8; ++p) {
      int fi = p * 256 + tid;
      int rr = fi >> 3, cc = (fi & 7) * 4;
      float4 v = *reinterpret_cast<const float4*>(
          A + (size_t)(r0 + rr) * NN + kt + cc);
      At[cc + 0][rr] = v.x; At[cc + 1][rr] = v.y;
      At[cc + 2][rr] = v.z; At[cc + 3][rr] = v.w;
    }
    // stage S: 32 k x 64 cols = 512 float4, 2 per thread
#pragma unroll
    for (int p = 0; p < 2; ++p) {
      int fi = p * 256 + tid;
      int rr = fi >> 4, cc = (fi & 15) * 4;
      float4 v = *reinterpret_cast<const float4*>(
          S + (size_t)(kt + rr) * KK + cc);
      *reinterpret_cast<float4*>(&Sl[rr][cc]) = v;
    }
    __syncthreads();
#pragma unroll 2
    for (int k = 0; k < KT; ++k) {
      float a0 = At[k][lane];
      float a1 = At[k][lane + 64];
      float a2 = At[k][lane + 128];
      float a3 = At[k][lane + 192];
      const float4* Sv = reinterpret_cast<const float4*>(&Sl[k][c0]);
      float4 s0 = Sv[0], s1 = Sv[1], s2 = Sv[2], s3 = Sv[3];
      float sc[16] = {s0.x, s0.y, s0.z, s0.w, s1.x, s1.y, s1.z, s1.w,
                      s2.x, s2.y, s2.z, s2.w, s3.x, s3.y, s3.z, s3.w};
#pragma unroll
      for (int q = 0; q < 16; ++q) {
        acc[0][q] = fmaf(a0, sc[q], acc[0][q]);
        acc[1][q] = fmaf(a1, sc[q], acc[1][q]);
        acc[2][q] = fmaf(a2, sc[q], acc[2][q]);
        acc[3][q] = fmaf(a3, sc[q], acc[3][q]);
      }
    }
    __syncthreads();
  }
#pragma unroll
  for (int r = 0; r < 4; ++r)
#pragma unroll
    for (int q = 0; q < 16; ++q)
      unsafeAtomicAdd(&AST[(size_t)(c0 + q) * NN + r0 + r * 64 + lane],
                      acc[r][q]);
}

// ---------------------------------------------------------------------------
// K2: CRAW[j*64+l] += sum_i S[i][l] * AST[j][i]  over an i-segment.
// ---------------------------------------------------------------------------
__global__ __launch_bounds__(256) void k_gemm_c(
    const float* __restrict__ S, const float* __restrict__ AST,
    float* __restrict__ CRAW) {
  const int j = blockIdx.x & 63;
  const int iseg = blockIdx.x >> 6;
  const int lane = threadIdx.x & 63;
  const int s4 = __builtin_amdgcn_readfirstlane(threadIdx.x >> 6);
  const int i0 = iseg * 1024 + s4 * 256;
  const float* astj = AST + (size_t)j * NN + i0;
  float acc = 0.0f;
  for (int i = 0; i < 256; i += 4) {
    float4 a4 = *reinterpret_cast<const float4*>(astj + i);
    const float* Srow = S + (size_t)(i0 + i) * KK + lane;
    acc = fmaf(a4.x, Srow[0 * KK], acc);
    acc = fmaf(a4.y, Srow[1 * KK], acc);
    acc = fmaf(a4.z, Srow[2 * KK], acc);
    acc = fmaf(a4.w, Srow[3 * KK], acc);
  }
  __shared__ float red[4][64];
  red[s4][lane] = acc;
  __syncthreads();
  if (threadIdx.x < 64) {
    unsafeAtomicAdd(&CRAW[j * 64 + lane],
                    red[0][lane] + red[1][lane] + red[2][lane] + red[3][lane]);
  }
}

// ---------------------------------------------------------------------------
// K3: D build + Prim MST + dgm0 + dgm1 (one block, LDS-resident).
// Also zeroes d_out for K4's atomic adds.
// ---------------------------------------------------------------------------
__global__ __launch_bounds__(256) void k_topo(
    const float* __restrict__ CRAW, float* __restrict__ DGM0,
    float* __restrict__ DGM1, float* __restrict__ out) {
  __shared__ float Dl[64 * 66];
  __shared__ float red[4];
  __shared__ float wsE[64];
  __shared__ int usE[64], vsE[64];
  __shared__ unsigned char msk[4096];
  __shared__ float death[4096];
  __shared__ float pers[4096];
  __shared__ float rv[4];
  __shared__ int ri[4];
  const int t = threadIdx.x;

  if (t == 0) out[0] = 0.0f;

  // 1) symmetrize + global max
  float lmax = -1e30f;
#pragma unroll
  for (int m = 0; m < 16; ++m) {
    int idx = t + 256 * m;
    int a = idx >> 6, b = idx & 63;
    float v = 0.5f * (CRAW[idx] + CRAW[b * 64 + a]);
    Dl[a * 66 + b] = v;
    lmax = fmaxf(lmax, v);
  }
  for (int o = 32; o > 0; o >>= 1) lmax = fmaxf(lmax, __shfl_xor(lmax, o));
  if ((t & 63) == 0) red[t >> 6] = lmax;
  __syncthreads();
  const float mx = fmaxf(fmaxf(red[0], red[1]), fmaxf(red[2], red[3]));
  const float inv = 1.0f / (mx + 1e-12f);
  __syncthreads();
#pragma unroll
  for (int m = 0; m < 16; ++m) {
    int idx = t + 256 * m;
    int a = idx >> 6, b = idx & 63;
    float v = 1.0f - Dl[a * 66 + b] * inv;
    Dl[a * 66 + b] = (a == b) ? 0.0f : v;
  }
  __syncthreads();

  // 2) Prim MST in wave 0 (lane = vertex v)
  if (t < 64) {
    const int lane = t;
    bool intree = (lane == 0);
    float key = Dl[0 * 66 + lane];
    int par = 0;
    for (int step = 0; step < 63; ++step) {
      float kv = intree ? 1e9f : key;
      int ki = lane;
      for (int o = 32; o > 0; o >>= 1) {
        float ov = __shfl_xor(kv, o);
        int oi = __shfl_xor(ki, o);
        if (ov < kv || (ov == kv && oi < ki)) { kv = ov; ki = oi; }
      }
      int pu = __shfl(par, ki);
      if (lane == 0) { wsE[step] = kv; usE[step] = pu; vsE[step] = ki; }
      if (lane == ki) intree = true;
      float dn = Dl[ki * 66 + lane];
      if (!intree && dn < key) { key = dn; par = ki; }
    }
  }
  __syncthreads();

  // 3) MST adjacency mask
  for (int idx = t; idx < 4096; idx += 256) msk[idx] = 0;
  __syncthreads();
  if (t < 63) {
    int u = usE[t], v = vsE[t];
    msk[u * 64 + v] = 1;
    msk[v * 64 + u] = 1;
  }
  __syncthreads();

  // 4) dgm0: rank-sort descending of [ws(63), 0]
  if (t < 64) {
    float wv = (t < 63) ? wsE[t] : 0.0f;
    int rank = 0;
    for (int o = 0; o < 64; ++o) {
      float wo = (o < 63) ? wsE[o] : 0.0f;
      rank += (wo > wv) || (wo == wv && o < t);
    }
    DGM0[rank * 2 + 0] = 0.0f;
    DGM0[rank * 2 + 1] = wv;
  }

  // 5) death & persistence for all pairs
  for (int p = t; p < 4096; p += 256) {
    int i = p >> 6, j = p & 63;
    float dij = Dl[i * 66 + j];
    float tmin = 1e9f;
#pragma unroll 8
    for (int k2 = 0; k2 < 64; ++k2) {
      float m2 = fmaxf(Dl[i * 66 + k2], Dl[j * 66 + k2]);
      tmin = fminf(tmin, (k2 == i || k2 == j) ? 1e9f : m2);
    }
    float de = fmaxf(dij, tmin);
    death[p] = de;
    bool valid = (j > i) && (!msk[p]);
    pers[p] = valid ? (de - dij) : -1.0f;
  }
  __syncthreads();

  // 6) top-64 of pers (lowest-index ties), write dgm1
  for (int r = 0; r < 64; ++r) {
    float bv = -1e30f;
    int bi = 0;
    for (int p = t; p < 4096; p += 256) {
      float v = pers[p];
      if (v > bv) { bv = v; bi = p; }
    }
    for (int o = 32; o > 0; o >>= 1) {
      float ov = __shfl_xor(bv, o);
      int oi = __shfl_xor(bi, o);
      if (ov > bv || (ov == bv && oi < bi)) { bv = ov; bi = oi; }
    }
    if ((t & 63) == 0) { rv[t >> 6] = bv; ri[t >> 6] = bi; }
    __syncthreads();
    if (t == 0) {
      for (int q = 1; q < 4; ++q)
        if (rv[q] > bv || (rv[q] == bv && ri[q] < bi)) { bv = rv[q]; bi = ri[q]; }
      bool keep = bv > 0.0f;
      int i = bi >> 6, j = bi & 63;
      DGM1[r * 2 + 0] = keep ? Dl[i * 66 + j] : 0.0f;
      DGM1[r * 2 + 1] = keep ? death[bi] : 0.0f;
      pers[bi] = -3.0f;
    }
    __syncthreads();
  }
}

// ---------------------------------------------------------------------------
// K4: Sinkhorn W1 (65x65, 300 iters), multiplicative domain, fp64.
// u = 1/(W v), v = 1/(W^T u) with W = exp(-C/eps): per phase a pure 65x65
// fp64 matvec + reciprocal -- zero transcendentals in the loop.
// fp64 because |log| <= C_max/eps + log64 ~ 105 (overflows fp32 range).
// Row/col-64 (mass 64) partials carried in pm[w][64]; u64/v64 deduped to
// one wave, shared via LDS across the existing barriers.
// ---------------------------------------------------------------------------
__global__ __launch_bounds__(512) void k_sinkhorn(
    const float* __restrict__ DGM0, const float* __restrict__ DGM1,
    const float* __restrict__ G0, const float* __restrict__ G1,
    const float* __restrict__ G2, const float* __restrict__ G3,
    float* __restrict__ out) {
  const int b = blockIdx.x;
  const float* X = (b & 1) ? DGM1 : DGM0;
  const float* Y = (b == 0) ? G0 : (b == 1) ? G1 : (b == 2) ? G2 : G3;

  __shared__ double Wd[65][66];   // exp(-C/eps), 34.3 KB
  __shared__ float Cf[65][66];    // C/eps (setup + final loss), 17.2 KB
  __shared__ double pmu[8][66];   // phase-u partials (col 64 = row-64 part)
  __shared__ double pmv[8][66];   // phase-v partials (col 64 = col-64 part)
  __shared__ double u64s, v64s;
  __shared__ float wsum[8];

  const int t = threadIdx.x;
  const int lane = t & 63;
  const int w = __builtin_amdgcn_readfirstlane(t >> 6);
  const float INVE = 100.0f;  // 1/eps

  for (int idx = t; idx < 65 * 65; idx += 512) {
    int i = idx / 65, j = idx - i * 65;
    float v;
    if (i < 64) {
      float xb = X[i * 2], xd = X[i * 2 + 1];
      if (j < 64)
        v = fmaxf(fabsf(xb - Y[j * 2]), fabsf(xd - Y[j * 2 + 1]));
      else
        v = 0.5f * (xd - xb);
    } else {
      v = (j < 64) ? 0.5f * (Y[j * 2 + 1] - Y[j * 2]) : 0.0f;
    }
    Cf[i][j] = v * INVE;
  }
  if (t == 0) v64s = 1.0;
  __syncthreads();
  for (int idx = t; idx < 65 * 65; idx += 512) {
    int i = idx / 65, j = idx - i * 65;
    Wd[i][j] = exp(-(double)Cf[i][j]);
  }
  __syncthreads();

  // register-resident W / C chunks (reused 300x)
  double WF[8], WG[8], WG64r[8], WC64r[8];
  float CeF[8], Ce64r[8];
#pragma unroll
  for (int q = 0; q < 8; ++q) {
    int jq = 8 * w + q;
    WF[q] = Wd[lane][jq];     // row=lane, col=jq   (phase u)
    WG[q] = Wd[jq][lane];     // row=jq, col=lane   (phase v)
    WG64r[q] = Wd[64][jq];    // row 64 chunk (lane-invariant)
    WC64r[q] = Wd[jq][64];    // col 64 chunk (lane-invariant)
    CeF[q] = Cf[lane][jq];
    Ce64r[q] = Cf[64][jq];
  }
  const double WF8 = Wd[lane][64];   // W[i=lane][64]
  const double W64c = Wd[64][lane];  // W[64][j=lane]
  const float CF8e = Cf[lane][64];

  double u = 1.0, v = 1.0;  // scalings, replicated per wave (lane = index)

  for (int it = 0; it < 300; ++it) {
    // ---- phase u main: partial (W v)_i over this wave's 8-col chunk ----
    {
      double part = 0.0, r64 = 0.0;
#pragma unroll
      for (int q = 0; q < 8; ++q) {
        double sv = rdlane(v, 8 * w + q);
        part = fma(WF[q], sv, part);
        r64 = fma(WG64r[q], sv, r64);
      }
      pmu[w][lane] = part;
      if (lane == 0) pmu[w][64] = r64;
    }
    __syncthreads();
    // ---- phase u merge ----
    {
      double s = pmu[0][lane];
#pragma unroll
      for (int q2 = 1; q2 < 8; ++q2) s += pmu[q2][lane];
      double v64u = v64s;  // fenced by the barrier above
      s = fma(WF8, v64u, s);
      u = 1.0 / s;  // a_i = 1 for i < 64
      if (w == 0) {
        double s64 = v64u;  // W[64][64] = 1
#pragma unroll
        for (int q2 = 0; q2 < 8; ++q2) s64 += pmu[q2][64];
        if (lane == 0) u64s = 64.0 / s64;
      }
    }
    // ---- phase v main: partial (W^T u)_j over this wave's 8-row chunk ----
    {
      double part = 0.0, c64 = 0.0;
#pragma unroll
      for (int q = 0; q < 8; ++q) {
        double su = rdlane(u, 8 * w + q);
        part = fma(WG[q], su, part);
        c64 = fma(WC64r[q], su, c64);
      }
      pmv[w][lane] = part;
      if (lane == 0) pmv[w][64] = c64;
    }
    __syncthreads();
    // ---- phase v merge ----
    {
      double s = pmv[0][lane];
#pragma unroll
      for (int q2 = 1; q2 < 8; ++q2) s += pmv[q2][lane];
      double u64u = u64s;  // fenced by the barrier above
      s = fma(W64c, u64u, s);
      v = 1.0 / s;  // b_j = 1 for j < 64
      if (w == 1) {
        double s64 = u64u;
#pragma unroll
        for (int q2 = 0; q2 < 8; ++q2) s64 += pmv[q2][64];
        if (lane == 0) v64s = 64.0 / s64;
      }
    }
  }
  __syncthreads();

  // ---- final: loss = eps * sum_ij u_i W_ij v_j * (C_ij/eps) ----
  const double u64u = u64s, v64u = v64s;
  double acc = 0.0, accU = 0.0;
#pragma unroll
  for (int q = 0; q < 8; ++q) {
    double sv = rdlane(v, 8 * w + q);
    acc += u * WF[q] * sv * (double)CeF[q];        // rows = lane
    accU += WG64r[q] * sv * (double)Ce64r[q];      // row 64 (lane-invariant)
  }
  accU *= u64u;
  if (w == 0) acc += u * WF8 * v64u * (double)CF8e;  // col 64, rows = lane
  // (64,64): C = 0 contributes nothing
  float af = (float)acc;
  for (int o = 32; o > 0; o >>= 1) af += __shfl_xor(af, o);
  if (lane == 0) wsum[w] = af + (float)accU;
  __syncthreads();
  if (t == 0) {
    float tot = 0.0f;
#pragma unroll
    for (int q = 0; q < 8; ++q) tot += wsum[q];
    atomicAdd(out, 0.1f * 0.01f * tot);  // LAMBDA * eps * sum(P * C/eps)
  }
}

// ---------------------------------------------------------------------------
extern "C" void kernel_launch(void* const* d_in, const int* in_sizes, int n_in,
                              void* d_out, int out_size, void* d_ws,
                              size_t ws_size, hipStream_t stream) {
  const float* A = (const float*)d_in[0];
  const float* S = (const float*)d_in[1];
  const float* G0 = (const float*)d_in[2];
  const float* G1 = (const float*)d_in[3];
  const float* G2 = (const float*)d_in[4];
  const float* G3 = (const float*)d_in[5];
  float* out = (float*)d_out;
  float* ws = (float*)d_ws;

  float* AST = ws + AST_OFF;
  float* CRAW = ws + CRAW_OFF;
  float* DGM0 = ws + DGM0_OFF;
  float* DGM1 = ws + DGM1_OFF;

  // zero AST (2 MB) + CRAW (16 KB) for atomic accumulation
  (void)hipMemsetAsync(AST, 0, (size_t)(64 * NN + 64 * 64) * sizeof(float),
                       stream);

  k_gemm_as<<<dim3(32 * KSPLIT), dim3(256), 0, stream>>>(A, S, AST);
  k_gemm_c<<<dim3(64 * 8), dim3(256), 0, stream>>>(S, AST, CRAW);
  k_topo<<<dim3(1), dim3(256), 0, stream>>>(CRAW, DGM0, DGM1, out);
  k_sinkhorn<<<dim3(4), dim3(512), 0, stream>>>(DGM0, DGM1, G0, G1, G2, G3,
                                                out);
}